// Round 10
// baseline (1415.959 us; speedup 1.0000x reference)
//
#include <hip/hip_runtime.h>
#include <hip/hip_fp16.h>

typedef _Float16 h8 __attribute__((ext_vector_type(8)));
typedef float f32x4 __attribute__((ext_vector_type(4)));

// 2-term split-product MFMA: A*B ~= Ah·Bh + Ah·Bl  (A pre-rounded to fp16)
__device__ __forceinline__ f32x4 mfma2(h8 ah, h8 bh, h8 bl, f32x4 c) {
    c = __builtin_amdgcn_mfma_f32_16x16x32_f16(ah, bh, c, 0, 0, 0);
    c = __builtin_amdgcn_mfma_f32_16x16x32_f16(ah, bl, c, 0, 0, 0);
    return c;
}

// ---- weight prep: for W[K][N] row-major, store hi/lo fp16 planes n-major ----
__launch_bounds__(256)
__global__ void wprep(const float* __restrict__ w_p1_1, const float* __restrict__ w_p1_2,
                      const float* __restrict__ w_p2_1, const float* __restrict__ w_p2_2,
                      const float* __restrict__ w_p3_1, const float* __restrict__ w_p3_2,
                      const float* __restrict__ w_u1, const float* __restrict__ w_u2,
                      _Float16* __restrict__ hb)
{
    int b = blockIdx.x;
    const float* src; int K, N, base; size_t off;
    if      (b < 16)  { src = w_p1_1; K = 64;  N = 64;  base = 0;   off = 0;      }
    else if (b < 32)  { src = w_p1_2; K = 64;  N = 64;  base = 16;  off = 8192;   }
    else if (b < 96)  { src = w_p2_1; K = 128; N = 128; base = 32;  off = 16384;  }
    else if (b < 160) { src = w_p2_2; K = 128; N = 128; base = 96;  off = 49152;  }
    else if (b < 304) { src = w_p3_1; K = 192; N = 192; base = 160; off = 81920;  }
    else if (b < 448) { src = w_p3_2; K = 192; N = 192; base = 304; off = 155648; }
    else if (b < 512) { src = w_u1;   K = 128; N = 128; base = 448; off = 229376; }
    else              { src = w_u2;   K = 128; N = 64;  base = 512; off = 262144; }
    int e = (b - base) * 256 + threadIdx.x;
    if (e < K * N) {
        int n = e / K, k = e - n * K;
        float x = src[k * N + n];
        _Float16 h = (_Float16)x;
        hb[off + e] = h;
        hb[off + (size_t)K * N + e] = (_Float16)(x - (float)h);
    }
}

// ---- layer-0 constant atom embeddings: a_const = b2 + relu(b1) @ W2 (fp32 exact) ----
__launch_bounds__(256)
__global__ void aconst_k(const float* __restrict__ b_p1_1, const float* __restrict__ w_p1_2,
                         const float* __restrict__ b_p1_2,
                         const float* __restrict__ b_p2_1, const float* __restrict__ w_p2_2,
                         const float* __restrict__ b_p2_2,
                         const float* __restrict__ b_p3_1, const float* __restrict__ w_p3_2,
                         const float* __restrict__ b_p3_2,
                         float* __restrict__ ac)
{
    int p = blockIdx.x;
    const float *b1, *w2, *b2; int D, off;
    if      (p == 0) { b1 = b_p1_1; w2 = w_p1_2; b2 = b_p1_2; D = 64;  off = 0;   }
    else if (p == 1) { b1 = b_p2_1; w2 = w_p2_2; b2 = b_p2_2; D = 128; off = 64;  }
    else             { b1 = b_p3_1; w2 = w_p3_2; b2 = b_p3_2; D = 192; off = 192; }
    int n = threadIdx.x;
    if (n < D) {
        float s = b2[n];
        for (int k = 0; k < D; ++k) {
            float h = b1[k];
            h = h > 0.f ? h : 0.f;
            s = fmaf(h, w2[k * D + n], s);
        }
        ac[off + n] = s;
    }
}

// ---- histogram: counts[6][n_obj] per (pred,slot), deg totals in counts[6] ----
__launch_bounds__(256)
__global__ void hist_k(const int* __restrict__ ei1, const int* __restrict__ ei2,
                       const int* __restrict__ ei3, int* __restrict__ counts,
                       int n_obj, int n1, int n2, int n3)
{
    int e = blockIdx.x * 256 + threadIdx.x;
    int t1 = n1, t2 = n1 + 2 * n2, t3 = t2 + 3 * n3;
    int o, j;
    if (e < t1) { o = ei1[e]; j = 0; }
    else if (e < t2) { int x = e - t1; o = ei2[x]; j = 1 + (x >= n2 ? 1 : 0); }
    else if (e < t3) { int y = e - t2; o = ei3[y]; j = 3 + (y >= n3 ? 1 : 0) + (y >= 2 * n3 ? 1 : 0); }
    else return;
    atomicAdd(&counts[(size_t)j * n_obj + o], 1);
    atomicAdd(&counts[(size_t)6 * n_obj + o], 1);
}

// ---- exclusive scan of deg -> rowptr (+cursor copy), single block ----
__launch_bounds__(1024)
__global__ void scan_k(const int* __restrict__ deg, int* __restrict__ rowptr,
                       int* __restrict__ cursor, int n)
{
    __shared__ int buf[1024];
    __shared__ int carry_s;
    int tid = threadIdx.x;
    if (tid == 0) carry_s = 0;
    __syncthreads();
    for (int base = 0; base < n; base += 4096) {
        int idx = base + tid * 4;
        int v[4];
#pragma unroll
        for (int k = 0; k < 4; ++k) { int i = idx + k; v[k] = (i < n) ? deg[i] : 0; }
        int tsum = v[0] + v[1] + v[2] + v[3];
        buf[tid] = tsum;
        __syncthreads();
        for (int off = 1; off < 1024; off <<= 1) {
            int t = (tid >= off) ? buf[tid - off] : 0;
            __syncthreads();
            buf[tid] += t;
            __syncthreads();
        }
        int run = buf[tid] - tsum + carry_s;
#pragma unroll
        for (int k = 0; k < 4; ++k) {
            int i = idx + k;
            if (i < n) { rowptr[i] = run; cursor[i] = run; }
            run += v[k];
        }
        __syncthreads();
        if (tid == 1023) carry_s += buf[1023];
        __syncthreads();
    }
    if (tid == 0) rowptr[n] = carry_s;
}

// ---- CSR inverse map: epos[e] = sorted position of entry e ----
__launch_bounds__(256)
__global__ void fill_k(const int* __restrict__ ei1, const int* __restrict__ ei2,
                       const int* __restrict__ ei3, int* __restrict__ cursor,
                       int* __restrict__ epos, int n1, int n2, int n3)
{
    int e = blockIdx.x * 256 + threadIdx.x;
    int t1 = n1, t2 = n1 + 2 * n2, t3 = t2 + 3 * n3;
    int o;
    if (e < t1) o = ei1[e];
    else if (e < t2) o = ei2[e - t1];
    else if (e < t3) o = ei3[e - t2];
    else return;
    epos[e] = atomicAdd(&cursor[o], 1);
}

// ---- layer-0 aggh[o][:] = fp16( sum_j counts[j][o] * chunk[j][:] ) ----
__launch_bounds__(256)
__global__ void bcast_k(const int* __restrict__ counts, const float* __restrict__ ac,
                        _Float16* __restrict__ aggh, int n_obj)
{
    __shared__ float ch[384];
    int tid = threadIdx.x;
    for (int i = tid; i < 384; i += 256) ch[i] = ac[i];
    __syncthreads();
    int i = blockIdx.x * 256 + tid;
    int o = i >> 3, q = i & 7;
    if (o < n_obj) {
        float c[6];
#pragma unroll
        for (int j = 0; j < 6; ++j) c[j] = (float)counts[(size_t)j * n_obj + o];
        h8 v;
#pragma unroll
        for (int comp = 0; comp < 8; ++comp) {
            int col = 8 * q + comp;
            float s = 0.f;
#pragma unroll
            for (int j = 0; j < 6; ++j) s = fmaf(c[j], ch[j * 64 + col], s);
            v[comp] = (_Float16)s;
        }
        *(h8*)(aggh + (size_t)o * 64 + 8 * q) = v;
    }
}

// ---- fused pred body; STORE=1: full-line chunk stores at CSR pos; STORE=0: atomics ----
template<int R, int STORE>
__device__ __forceinline__ void pred_body(
    char* smem,
    const _Float16* __restrict__ objh, const int* __restrict__ ei,
    const int* __restrict__ epos, int cbase,
    const _Float16* __restrict__ W1h, const _Float16* __restrict__ W1l,
    const float* __restrict__ B1,
    const _Float16* __restrict__ W2h, const _Float16* __restrict__ W2l,
    const float* __restrict__ B2,
    _Float16* __restrict__ aggh, _Float16* __restrict__ chunks,
    int n_atoms, int blk)
{
    constexpr int D = 64 * R;
    constexpr int KC = D / 32;
    constexpr int LDA = D + 8;
    _Float16* Ah = (_Float16*)smem;
    int* eis = (int*)(Ah + 64 * LDA);

    const int tid = threadIdx.x;
    const int wave = tid >> 6, lane = tid & 63;
    const int r = lane & 15, g = lane >> 4;
    const int a_base = blk * 64;
    const int tb = wave * R;

    for (int i = tid; i < R * 64; i += 256) {
        int s = i >> 6, a = i & 63;
        int ag = a_base + a; if (ag >= n_atoms) ag = n_atoms - 1;
        eis[i] = ei[s * n_atoms + ag];
    }
    __syncthreads();
    {
        h8 vv[2 * R];
#pragma unroll
        for (int i = 0; i < 2 * R; ++i) {
            int f = tid + 256 * i;
            int rowslot = f >> 3, c = f & 7;
            int s = rowslot >> 6, a = rowslot & 63;
            vv[i] = *(const h8*)(objh + (size_t)eis[s * 64 + a] * 64 + c * 8);
        }
#pragma unroll
        for (int i = 0; i < 2 * R; ++i) {
            int f = tid + 256 * i;
            int rowslot = f >> 3, c = f & 7;
            int s = rowslot >> 6, a = rowslot & 63;
            *(h8*)(Ah + a * LDA + s * 64 + c * 8) = vv[i];
        }
    }
    __syncthreads();

    f32x4 z = {0.f, 0.f, 0.f, 0.f};
    f32x4 acc[4][R];
#pragma unroll
    for (int rt = 0; rt < 4; ++rt)
#pragma unroll
        for (int t = 0; t < R; ++t) acc[rt][t] = z;

    // ---- GEMM1 ----
    {
        h8 bh[2][R], bl[2][R];
#pragma unroll
        for (int t = 0; t < R; ++t) {
            size_t wo = (size_t)((tb + t) * 16 + r) * D + g * 8;
            bh[0][t] = *(const h8*)(W1h + wo);
            bl[0][t] = *(const h8*)(W1l + wo);
        }
#pragma unroll
        for (int kc = 0; kc < KC; ++kc) {
            const int cur = kc & 1, nxt = cur ^ 1;
            if (kc + 1 < KC) {
#pragma unroll
                for (int t = 0; t < R; ++t) {
                    size_t wo = (size_t)((tb + t) * 16 + r) * D + (kc + 1) * 32 + g * 8;
                    bh[nxt][t] = *(const h8*)(W1h + wo);
                    bl[nxt][t] = *(const h8*)(W1l + wo);
                }
            }
            const int ko = kc * 32 + g * 8;
            h8 ah[4];
#pragma unroll
            for (int rt = 0; rt < 4; ++rt)
                ah[rt] = *(const h8*)(Ah + (rt * 16 + r) * LDA + ko);
#pragma unroll
            for (int t = 0; t < R; ++t)
#pragma unroll
                for (int rt = 0; rt < 4; ++rt)
                    acc[rt][t] = mfma2(ah[rt], bh[cur][t], bl[cur][t], acc[rt][t]);
        }
    }
    __syncthreads();
#pragma unroll
    for (int t = 0; t < R; ++t) {
        int col = (tb + t) * 16 + r;
        float b1 = B1[col];
#pragma unroll
        for (int rt = 0; rt < 4; ++rt)
#pragma unroll
            for (int q = 0; q < 4; ++q) {
                int row = rt * 16 + g * 4 + q;
                float h = acc[rt][t][q] + b1;
                h = h > 0.f ? h : 0.f;
                Ah[row * LDA + col] = (_Float16)h;
            }
    }
    __syncthreads();

    // ---- GEMM2 ----
#pragma unroll
    for (int rt = 0; rt < 4; ++rt)
#pragma unroll
        for (int t = 0; t < R; ++t) acc[rt][t] = z;
    {
        h8 bh[2][R], bl[2][R];
#pragma unroll
        for (int t = 0; t < R; ++t) {
            size_t wo = (size_t)((tb + t) * 16 + r) * D + g * 8;
            bh[0][t] = *(const h8*)(W2h + wo);
            bl[0][t] = *(const h8*)(W2l + wo);
        }
#pragma unroll
        for (int kc = 0; kc < KC; ++kc) {
            const int cur = kc & 1, nxt = cur ^ 1;
            if (kc + 1 < KC) {
#pragma unroll
                for (int t = 0; t < R; ++t) {
                    size_t wo = (size_t)((tb + t) * 16 + r) * D + (kc + 1) * 32 + g * 8;
                    bh[nxt][t] = *(const h8*)(W2h + wo);
                    bl[nxt][t] = *(const h8*)(W2l + wo);
                }
            }
            const int ko = kc * 32 + g * 8;
            h8 ah[4];
#pragma unroll
            for (int rt = 0; rt < 4; ++rt)
                ah[rt] = *(const h8*)(Ah + (rt * 16 + r) * LDA + ko);
#pragma unroll
            for (int t = 0; t < R; ++t)
#pragma unroll
                for (int rt = 0; rt < 4; ++rt)
                    acc[rt][t] = mfma2(ah[rt], bh[cur][t], bl[cur][t], acc[rt][t]);
        }
    }

    if (STORE) {
        // stage output in Ah (A data fully consumed), then full-line stores at CSR pos
        __syncthreads();
#pragma unroll
        for (int t = 0; t < R; ++t) {
            int col = (tb + t) * 16 + r;
            float b2 = B2[col];
            int s = col >> 6, cc = col & 63;
#pragma unroll
            for (int rt = 0; rt < 4; ++rt)
#pragma unroll
                for (int q = 0; q < 4; ++q) {
                    int row = rt * 16 + g * 4 + q;
                    Ah[row * LDA + s * 64 + cc] = (_Float16)(acc[rt][t][q] + b2);
                }
        }
        __syncthreads();
#pragma unroll
        for (int p = 0; p < 2 * R; ++p) {
            int i = p * 32 + (tid >> 3);      // chunk-row index: s*64 + a
            int s = i >> 6, a = i & 63;
            int c8 = tid & 7;
            int atom = a_base + a;
            if (atom < n_atoms) {
                int pos = epos[cbase + s * n_atoms + atom];
                *(h8*)(chunks + (size_t)pos * 64 + c8 * 8) =
                    *(const h8*)(Ah + a * LDA + s * 64 + c8 * 8);
            }
        }
    } else {
#pragma unroll
        for (int t = 0; t < R; ++t) {
            int col = (tb + t) * 16 + r;
            float b2 = B2[col];
            int s = col >> 6, cc = col & 63;
#pragma unroll
            for (int rt = 0; rt < 4; ++rt)
#pragma unroll
                for (int q = 0; q < 4; ++q) {
                    int row = rt * 16 + g * 4 + q;
                    int atom = a_base + row;
                    float v = acc[rt][t][q] + b2;
                    float v2 = __shfl_xor(v, 1);
                    if (atom < n_atoms && (r & 1) == 0) {
                        __half2 hv = __floats2half2_rn(v, v2);
                        unsafeAtomicAdd((__half2*)(aggh + (size_t)eis[s * 64 + row] * 64 + cc), hv);
                    }
                }
        }
    }
}

template<int STORE>
__launch_bounds__(256, 6)
__global__ void pred_all(const _Float16* __restrict__ objh, _Float16* __restrict__ aggh,
                         _Float16* __restrict__ chunks, const int* __restrict__ epos,
                         const int* __restrict__ ei1, const int* __restrict__ ei2,
                         const int* __restrict__ ei3,
                         const _Float16* __restrict__ hb,
                         const float* __restrict__ b_p1_1, const float* __restrict__ b_p1_2,
                         const float* __restrict__ b_p2_1, const float* __restrict__ b_p2_2,
                         const float* __restrict__ b_p3_1, const float* __restrict__ b_p3_2,
                         int n1, int n2, int n3, int nb3, int nb2)
{
    extern __shared__ char smem[];
    int b = blockIdx.x;
    if (b < nb3) {
        pred_body<3, STORE>(smem, objh, ei3, epos, n1 + 2 * n2,
                            hb + 81920, hb + 118784, b_p3_1,
                            hb + 155648, hb + 192512, b_p3_2, aggh, chunks, n3, b);
    } else if (b < nb3 + nb2) {
        pred_body<2, STORE>(smem, objh, ei2, epos, n1,
                            hb + 16384, hb + 32768, b_p2_1,
                            hb + 49152, hb + 65536, b_p2_2, aggh, chunks, n2, b - nb3);
    } else {
        pred_body<1, STORE>(smem, objh, ei1, epos, 0,
                            hb + 0, hb + 4096, b_p1_1,
                            hb + 8192, hb + 12288, b_p1_2, aggh, chunks, n1, b - nb3 - nb2);
    }
}

// ---- fused fanin (contiguous CSR stream of chunk rows) + update MLP ----
__launch_bounds__(256, 4)
__global__ void fanin_update(_Float16* __restrict__ objh,
                             const _Float16* __restrict__ chunks,
                             const int* __restrict__ rowptr,
                             const _Float16* __restrict__ W1h, const _Float16* __restrict__ W1l,
                             const float* __restrict__ B1,
                             const _Float16* __restrict__ W2h, const _Float16* __restrict__ W2l,
                             const float* __restrict__ B2,
                             int n_obj, int last, float* __restrict__ aggf)
{
    constexpr int LDA = 136;
    __shared__ _Float16 Ah[64 * LDA];

    const int tid = threadIdx.x;
    const int wave = tid >> 6, lane = tid & 63;
    const int r = lane & 15, g = lane >> 4;
    const int a_base = blockIdx.x * 64;

    // phase A: 4 threads per object, 16 cols (32 B) each; contiguous chunk rows
    const int o_local = tid >> 2, part = tid & 3;
    const int o = a_base + o_local;
    const bool valid = o < n_obj;
    const int b = valid ? rowptr[o] : 0;
    const int e2 = valid ? rowptr[o + 1] : 0;
    float s[16];
#pragma unroll
    for (int j = 0; j < 16; ++j) s[j] = 0.f;
    for (int i = b; i < e2; ++i) {
        const h8* cp = (const h8*)(chunks + (size_t)i * 64 + part * 16);
        h8 v0 = cp[0], v1 = cp[1];
#pragma unroll
        for (int j = 0; j < 8; ++j) { s[j] += (float)v0[j]; s[8 + j] += (float)v1[j]; }
    }
    {
        int oc = valid ? o : n_obj - 1;
        h8 u0 = *(const h8*)(objh + (size_t)oc * 64 + part * 16);
        h8 u1 = *(const h8*)(objh + (size_t)oc * 64 + part * 16 + 8);
        *(h8*)(Ah + o_local * LDA + part * 16) = u0;
        *(h8*)(Ah + o_local * LDA + part * 16 + 8) = u1;
        h8 a0, a1;
#pragma unroll
        for (int j = 0; j < 8; ++j) { a0[j] = (_Float16)s[j]; a1[j] = (_Float16)s[8 + j]; }
        *(h8*)(Ah + o_local * LDA + 64 + part * 16) = a0;
        *(h8*)(Ah + o_local * LDA + 64 + part * 16 + 8) = a1;
    }
    __syncthreads();

    // phase B: MLP_u 128->128(relu)->64
    f32x4 z = {0.f, 0.f, 0.f, 0.f};
    f32x4 acc[4][2];
#pragma unroll
    for (int rt = 0; rt < 4; ++rt) { acc[rt][0] = z; acc[rt][1] = z; }
    {
        h8 bh[2][2], bl[2][2];
#pragma unroll
        for (int t = 0; t < 2; ++t) {
            size_t wo = (size_t)((wave * 2 + t) * 16 + r) * 128 + g * 8;
            bh[0][t] = *(const h8*)(W1h + wo);
            bl[0][t] = *(const h8*)(W1l + wo);
        }
#pragma unroll
        for (int kc = 0; kc < 4; ++kc) {
            const int cur = kc & 1, nxt = cur ^ 1;
            if (kc + 1 < 4) {
#pragma unroll
                for (int t = 0; t < 2; ++t) {
                    size_t wo = (size_t)((wave * 2 + t) * 16 + r) * 128 + (kc + 1) * 32 + g * 8;
                    bh[nxt][t] = *(const h8*)(W1h + wo);
                    bl[nxt][t] = *(const h8*)(W1l + wo);
                }
            }
            const int ko = kc * 32 + g * 8;
            h8 ah[4];
#pragma unroll
            for (int rt = 0; rt < 4; ++rt)
                ah[rt] = *(const h8*)(Ah + (rt * 16 + r) * LDA + ko);
#pragma unroll
            for (int t = 0; t < 2; ++t)
#pragma unroll
                for (int rt = 0; rt < 4; ++rt)
                    acc[rt][t] = mfma2(ah[rt], bh[cur][t], bl[cur][t], acc[rt][t]);
        }
    }
    __syncthreads();
#pragma unroll
    for (int t = 0; t < 2; ++t) {
        int col = (wave * 2 + t) * 16 + r;
        float b1 = B1[col];
#pragma unroll
        for (int rt = 0; rt < 4; ++rt)
#pragma unroll
            for (int q = 0; q < 4; ++q) {
                int row = rt * 16 + g * 4 + q;
                float h = acc[rt][t][q] + b1;
                h = h > 0.f ? h : 0.f;
                Ah[row * LDA + col] = (_Float16)h;
            }
    }
    __syncthreads();

    f32x4 acc2[4];
#pragma unroll
    for (int rt = 0; rt < 4; ++rt) acc2[rt] = z;
    {
        h8 bh[2], bl[2];
        {
            size_t wo = (size_t)(wave * 16 + r) * 128 + g * 8;
            bh[0] = *(const h8*)(W2h + wo);
            bl[0] = *(const h8*)(W2l + wo);
        }
#pragma unroll
        for (int kc = 0; kc < 4; ++kc) {
            const int cur = kc & 1, nxt = cur ^ 1;
            if (kc + 1 < 4) {
                size_t wo = (size_t)(wave * 16 + r) * 128 + (kc + 1) * 32 + g * 8;
                bh[nxt] = *(const h8*)(W2h + wo);
                bl[nxt] = *(const h8*)(W2l + wo);
            }
            const int ko = kc * 32 + g * 8;
#pragma unroll
            for (int rt = 0; rt < 4; ++rt) {
                h8 ah = *(const h8*)(Ah + (rt * 16 + r) * LDA + ko);
                acc2[rt] = mfma2(ah, bh[cur], bl[cur], acc2[rt]);
            }
        }
    }
    {
        int col = wave * 16 + r;
        float b2 = B2[col];
#pragma unroll
        for (int rt = 0; rt < 4; ++rt)
#pragma unroll
            for (int q = 0; q < 4; ++q) {
                int row = a_base + rt * 16 + g * 4 + q;
                if (row < n_obj) {
                    float v = acc2[rt][q] + b2;
                    if (last) aggf[(size_t)row * 64 + col] = v;
                    else objh[(size_t)row * 64 + col] = (_Float16)v;
                }
            }
    }
}

// ---- layer-0 / fallback update (reads fp16 aggh) ----
template<int FIRST>
__launch_bounds__(256, 4)
__global__ void update_mfma(_Float16* __restrict__ objh, _Float16* __restrict__ aggh,
                            const _Float16* __restrict__ W1h, const _Float16* __restrict__ W1l,
                            const float* __restrict__ B1,
                            const _Float16* __restrict__ W2h, const _Float16* __restrict__ W2l,
                            const float* __restrict__ B2,
                            int n_obj, int zero_agg, int last, float* __restrict__ aggf)
{
    constexpr int LDA = 136;
    __shared__ _Float16 Ah[64 * LDA];

    const int tid = threadIdx.x;
    const int wave = tid >> 6, lane = tid & 63;
    const int r = lane & 15, g = lane >> 4;
    const int a_base = blockIdx.x * 64;

    {
#pragma unroll
        for (int i = 0; i < 4; ++i) {
            int f = tid + 256 * i;
            int a = f >> 4, c = f & 15;
            int rg = a_base + a; if (rg >= n_obj) rg = n_obj - 1;
            h8 v;
            if (c < 8) {
                if (FIRST) v = (h8)(_Float16)0.f;
                else v = *(const h8*)(objh + (size_t)rg * 64 + c * 8);
            } else {
                v = *(const h8*)(aggh + (size_t)rg * 64 + (c - 8) * 8);
            }
            *(h8*)(Ah + a * LDA + c * 8) = v;
        }
    }
    __syncthreads();

    f32x4 z = {0.f, 0.f, 0.f, 0.f};
    f32x4 acc[4][2];
#pragma unroll
    for (int rt = 0; rt < 4; ++rt) { acc[rt][0] = z; acc[rt][1] = z; }
    {
        h8 bh[2][2], bl[2][2];
#pragma unroll
        for (int t = 0; t < 2; ++t) {
            size_t wo = (size_t)((wave * 2 + t) * 16 + r) * 128 + g * 8;
            bh[0][t] = *(const h8*)(W1h + wo);
            bl[0][t] = *(const h8*)(W1l + wo);
        }
#pragma unroll
        for (int kc = 0; kc < 4; ++kc) {
            const int cur = kc & 1, nxt = cur ^ 1;
            if (kc + 1 < 4) {
#pragma unroll
                for (int t = 0; t < 2; ++t) {
                    size_t wo = (size_t)((wave * 2 + t) * 16 + r) * 128 + (kc + 1) * 32 + g * 8;
                    bh[nxt][t] = *(const h8*)(W1h + wo);
                    bl[nxt][t] = *(const h8*)(W1l + wo);
                }
            }
            const int ko = kc * 32 + g * 8;
            h8 ah[4];
#pragma unroll
            for (int rt = 0; rt < 4; ++rt)
                ah[rt] = *(const h8*)(Ah + (rt * 16 + r) * LDA + ko);
#pragma unroll
            for (int t = 0; t < 2; ++t)
#pragma unroll
                for (int rt = 0; rt < 4; ++rt)
                    acc[rt][t] = mfma2(ah[rt], bh[cur][t], bl[cur][t], acc[rt][t]);
        }
    }
    __syncthreads();
#pragma unroll
    for (int t = 0; t < 2; ++t) {
        int col = (wave * 2 + t) * 16 + r;
        float b1 = B1[col];
#pragma unroll
        for (int rt = 0; rt < 4; ++rt)
#pragma unroll
            for (int q = 0; q < 4; ++q) {
                int row = rt * 16 + g * 4 + q;
                float h = acc[rt][t][q] + b1;
                h = h > 0.f ? h : 0.f;
                Ah[row * LDA + col] = (_Float16)h;
            }
    }
    __syncthreads();

    f32x4 acc2[4];
#pragma unroll
    for (int rt = 0; rt < 4; ++rt) acc2[rt] = z;
    {
        h8 bh[2], bl[2];
        {
            size_t wo = (size_t)(wave * 16 + r) * 128 + g * 8;
            bh[0] = *(const h8*)(W2h + wo);
            bl[0] = *(const h8*)(W2l + wo);
        }
#pragma unroll
        for (int kc = 0; kc < 4; ++kc) {
            const int cur = kc & 1, nxt = cur ^ 1;
            if (kc + 1 < 4) {
                size_t wo = (size_t)(wave * 16 + r) * 128 + (kc + 1) * 32 + g * 8;
                bh[nxt] = *(const h8*)(W2h + wo);
                bl[nxt] = *(const h8*)(W2l + wo);
            }
            const int ko = kc * 32 + g * 8;
#pragma unroll
            for (int rt = 0; rt < 4; ++rt) {
                h8 ah = *(const h8*)(Ah + (rt * 16 + r) * LDA + ko);
                acc2[rt] = mfma2(ah, bh[cur], bl[cur], acc2[rt]);
            }
        }
    }
    __syncthreads();
    {
        int col = wave * 16 + r;
        float b2 = B2[col];
#pragma unroll
        for (int rt = 0; rt < 4; ++rt)
#pragma unroll
            for (int q = 0; q < 4; ++q) {
                int row = a_base + rt * 16 + g * 4 + q;
                if (row < n_obj) {
                    float v = acc2[rt][q] + b2;
                    if (last) aggf[(size_t)row * 64 + col] = v;
                    else objh[(size_t)row * 64 + col] = (_Float16)v;
                }
            }
    }
    if (zero_agg) {
        h8 zz = (h8)(_Float16)0.f;
#pragma unroll
        for (int i = 0; i < 2; ++i) {
            int f = tid + 256 * i;
            int a = f >> 3, q = f & 7;
            int rg = a_base + a;
            if (rg < n_obj) *(h8*)(aggh + (size_t)rg * 64 + q * 8) = zz;
        }
    }
}

__global__ void pool_kernel(const float* __restrict__ obj, const int* __restrict__ batch,
                            float* __restrict__ pooled, int n_obj)
{
    int i = blockIdx.x * 256 + threadIdx.x;
    int row = i >> 4, q = i & 15;
    if (row < n_obj) {
        float4 v = ((const float4*)obj)[(size_t)row * 16 + q];
        int g = batch[row];
        float* p = pooled + g * 64 + 4 * q;
        atomicAdd(p + 0, v.x);
        atomicAdd(p + 1, v.y);
        atomicAdd(p + 2, v.z);
        atomicAdd(p + 3, v.w);
    }
}

__launch_bounds__(128)
__global__ void readout_kernel(const float* __restrict__ pooled,
                               const float* __restrict__ w1, const float* __restrict__ b1,
                               const float* __restrict__ w2, const float* __restrict__ b2,
                               float* __restrict__ out)
{
    int g = blockIdx.x, c = threadIdx.x;
    __shared__ float xs[64];
    __shared__ float red[2];
    if (c < 64) xs[c] = pooled[g * 64 + c];
    __syncthreads();
    float h = b1[c];
#pragma unroll
    for (int k = 0; k < 64; ++k) h = fmaf(xs[k], w1[k * 128 + c], h);
    float v = fmaxf(h, 0.f) * w2[c];
#pragma unroll
    for (int off = 32; off > 0; off >>= 1) v += __shfl_down(v, off);
    if ((c & 63) == 0) red[c >> 6] = v;
    __syncthreads();
    if (c == 0) out[g] = red[0] + red[1] + b2[0];
}

static inline size_t align_up(size_t x) { return (x + 255) & ~(size_t)255; }

extern "C" void kernel_launch(void* const* d_in, const int* in_sizes, int n_in,
                              void* d_out, int out_size, void* d_ws, size_t ws_size,
                              hipStream_t stream)
{
    const float* w_p1_1 = (const float*)d_in[4];
    const float* b_p1_1 = (const float*)d_in[5];
    const float* w_p1_2 = (const float*)d_in[6];
    const float* b_p1_2 = (const float*)d_in[7];
    const float* w_p2_1 = (const float*)d_in[8];
    const float* b_p2_1 = (const float*)d_in[9];
    const float* w_p2_2 = (const float*)d_in[10];
    const float* b_p2_2 = (const float*)d_in[11];
    const float* w_p3_1 = (const float*)d_in[12];
    const float* b_p3_1 = (const float*)d_in[13];
    const float* w_p3_2 = (const float*)d_in[14];
    const float* b_p3_2 = (const float*)d_in[15];
    const float* w_u1 = (const float*)d_in[16];
    const float* b_u1 = (const float*)d_in[17];
    const float* w_u2 = (const float*)d_in[18];
    const float* b_u2 = (const float*)d_in[19];
    const float* w_r1 = (const float*)d_in[20];
    const float* b_r1 = (const float*)d_in[21];
    const float* w_r2 = (const float*)d_in[22];
    const float* b_r2 = (const float*)d_in[23];
    const int* ei_p1 = (const int*)d_in[24];
    const int* ei_p2 = (const int*)d_in[25];
    const int* ei_p3 = (const int*)d_in[26];
    const int* batch = (const int*)d_in[27];

    const int n_obj = in_sizes[0];
    const int n_p1 = in_sizes[24];
    const int n_p2 = in_sizes[25] / 2;
    const int n_p3 = in_sizes[26] / 3;
    const int E = n_p1 + 2 * n_p2 + 3 * n_p3;

    char* base = (char*)d_ws;
    size_t off = 0;
    _Float16* objh = (_Float16*)(base + off); off = align_up(off + (size_t)n_obj * 64 * 2);
    _Float16* aggh = (_Float16*)(base + off); off = align_up(off + (size_t)n_obj * 64 * 2);
    float* aggf = (float*)(base + off);       off = align_up(off + (size_t)n_obj * 64 * 4);
    float* pooled = (float*)(base + off);     off = align_up(off + (size_t)out_size * 64 * 4);
    _Float16* hb = (_Float16*)(base + off);   off = align_up(off + (size_t)278528 * 2);
    int* counts = (int*)(base + off);         off = align_up(off + (size_t)7 * n_obj * 4);
    int* deg = counts + (size_t)6 * n_obj;
    int* rowptr = (int*)(base + off);         off = align_up(off + ((size_t)n_obj + 1) * 4);
    int* cursor = (int*)(base + off);         off = align_up(off + (size_t)n_obj * 4);
    int* epos = (int*)(base + off);           off = align_up(off + (size_t)E * 4);
    _Float16* chunks = (_Float16*)(base + off); off = align_up(off + (size_t)E * 64 * 2);
    const bool csr_ok = off <= ws_size;
    float* ac = pooled;   // 384 floats; pooled re-zeroed later

    const int nb3 = (n_p3 + 63) / 64, nb2 = (n_p2 + 63) / 64, nb1 = (n_p1 + 63) / 64;
    const int pred_smem = 64 * (192 + 8) * 2 + 3 * 64 * 4;  // 26368 B

    wprep<<<544, 256, 0, stream>>>(w_p1_1, w_p1_2, w_p2_1, w_p2_2, w_p3_1, w_p3_2,
                                   w_u1, w_u2, hb);
    aconst_k<<<3, 256, 0, stream>>>(b_p1_1, w_p1_2, b_p1_2, b_p2_1, w_p2_2, b_p2_2,
                                    b_p3_1, w_p3_2, b_p3_2, ac);
    hipMemsetAsync(counts, 0, (size_t)7 * n_obj * sizeof(int), stream);
    hist_k<<<(E + 255) / 256, 256, 0, stream>>>(ei_p1, ei_p2, ei_p3, counts,
                                                n_obj, n_p1, n_p2, n_p3);
    if (csr_ok) {
        scan_k<<<1, 1024, 0, stream>>>(deg, rowptr, cursor, n_obj);
        fill_k<<<(E + 255) / 256, 256, 0, stream>>>(ei_p1, ei_p2, ei_p3, cursor, epos,
                                                    n_p1, n_p2, n_p3);
    }
    bcast_k<<<((size_t)n_obj * 8 + 255) / 256, 256, 0, stream>>>(counts, ac, aggh, n_obj);
    // layer 0 update (obj treated as zeros) -> objh
    update_mfma<1><<<(n_obj + 63) / 64, 256, 0, stream>>>(
        objh, aggh, hb + 229376, hb + 245760, b_u1, hb + 262144, hb + 270336, b_u2,
        n_obj, csr_ok ? 0 : 1, 0, aggf);
    if (csr_ok) {
        for (int l = 1; l < 3; ++l) {
            pred_all<1><<<nb3 + nb2 + nb1, 256, pred_smem, stream>>>(
                objh, aggh, chunks, epos, ei_p1, ei_p2, ei_p3, hb,
                b_p1_1, b_p1_2, b_p2_1, b_p2_2, b_p3_1, b_p3_2,
                n_p1, n_p2, n_p3, nb3, nb2);
            fanin_update<<<(n_obj + 63) / 64, 256, 0, stream>>>(
                objh, chunks, rowptr,
                hb + 229376, hb + 245760, b_u1, hb + 262144, hb + 270336, b_u2,
                n_obj, l == 2 ? 1 : 0, aggf);
        }
    } else {
        for (int l = 1; l < 3; ++l) {
            pred_all<0><<<nb3 + nb2 + nb1, 256, pred_smem, stream>>>(
                objh, aggh, chunks, epos, ei_p1, ei_p2, ei_p3, hb,
                b_p1_1, b_p1_2, b_p2_1, b_p2_2, b_p3_1, b_p3_2,
                n_p1, n_p2, n_p3, nb3, nb2);
            update_mfma<0><<<(n_obj + 63) / 64, 256, 0, stream>>>(
                objh, aggh, hb + 229376, hb + 245760, b_u1, hb + 262144, hb + 270336, b_u2,
                n_obj, l < 2 ? 1 : 0, l == 2 ? 1 : 0, aggf);
        }
    }
    hipMemsetAsync(pooled, 0, (size_t)out_size * 64 * sizeof(float), stream);
    pool_kernel<<<((size_t)n_obj * 16 + 255) / 256, 256, 0, stream>>>(aggf, batch, pooled, n_obj);
    readout_kernel<<<out_size, 128, 0, stream>>>(pooled, w_r1, b_r1, w_r2, b_r2, (float*)d_out);
}

// Round 11
// 1303.279 us; speedup vs baseline: 1.0865x; 1.0865x over previous
//
#include <hip/hip_runtime.h>
#include <hip/hip_fp16.h>

typedef _Float16 h8 __attribute__((ext_vector_type(8)));
typedef float f32x4 __attribute__((ext_vector_type(4)));

// 2-term split-product MFMA: A*B ~= Ah·Bh + Ah·Bl  (A pre-rounded to fp16)
__device__ __forceinline__ f32x4 mfma2(h8 ah, h8 bh, h8 bl, f32x4 c) {
    c = __builtin_amdgcn_mfma_f32_16x16x32_f16(ah, bh, c, 0, 0, 0);
    c = __builtin_amdgcn_mfma_f32_16x16x32_f16(ah, bl, c, 0, 0, 0);
    return c;
}

// ---- fused setup: wprep (blocks 0..543) + aconst (544..546) + hist (547..) ----
__launch_bounds__(256)
__global__ void setup_k(const float* __restrict__ w_p1_1, const float* __restrict__ w_p1_2,
                        const float* __restrict__ w_p2_1, const float* __restrict__ w_p2_2,
                        const float* __restrict__ w_p3_1, const float* __restrict__ w_p3_2,
                        const float* __restrict__ w_u1, const float* __restrict__ w_u2,
                        _Float16* __restrict__ hb,
                        const float* __restrict__ b_p1_1, const float* __restrict__ b_p1_2,
                        const float* __restrict__ b_p2_1, const float* __restrict__ b_p2_2,
                        const float* __restrict__ b_p3_1, const float* __restrict__ b_p3_2,
                        float* __restrict__ ac,
                        const int* __restrict__ ei1, const int* __restrict__ ei2,
                        const int* __restrict__ ei3, int* __restrict__ counts,
                        int n_obj, int n1, int n2, int n3)
{
    int b = blockIdx.x;
    if (b < 544) {
        const float* src; int K, N, base; size_t off;
        if      (b < 16)  { src = w_p1_1; K = 64;  N = 64;  base = 0;   off = 0;      }
        else if (b < 32)  { src = w_p1_2; K = 64;  N = 64;  base = 16;  off = 8192;   }
        else if (b < 96)  { src = w_p2_1; K = 128; N = 128; base = 32;  off = 16384;  }
        else if (b < 160) { src = w_p2_2; K = 128; N = 128; base = 96;  off = 49152;  }
        else if (b < 304) { src = w_p3_1; K = 192; N = 192; base = 160; off = 81920;  }
        else if (b < 448) { src = w_p3_2; K = 192; N = 192; base = 304; off = 155648; }
        else if (b < 512) { src = w_u1;   K = 128; N = 128; base = 448; off = 229376; }
        else              { src = w_u2;   K = 128; N = 64;  base = 512; off = 262144; }
        int e = (b - base) * 256 + threadIdx.x;
        if (e < K * N) {
            int n = e / K, k = e - n * K;
            float x = src[k * N + n];
            _Float16 h = (_Float16)x;
            hb[off + e] = h;
            hb[off + (size_t)K * N + e] = (_Float16)(x - (float)h);
        }
    } else if (b < 547) {
        int p = b - 544;
        const float *b1, *w2, *b2; int D, off;
        if      (p == 0) { b1 = b_p1_1; w2 = w_p1_2; b2 = b_p1_2; D = 64;  off = 0;   }
        else if (p == 1) { b1 = b_p2_1; w2 = w_p2_2; b2 = b_p2_2; D = 128; off = 64;  }
        else             { b1 = b_p3_1; w2 = w_p3_2; b2 = b_p3_2; D = 192; off = 192; }
        int n = threadIdx.x;
        if (n < D) {
            float s = b2[n];
            for (int k = 0; k < D; ++k) {
                float h = b1[k];
                h = h > 0.f ? h : 0.f;
                s = fmaf(h, w2[k * D + n], s);
            }
            ac[off + n] = s;
        }
    } else {
        int e = (b - 547) * 256 + threadIdx.x;
        int t1 = n1, t2 = n1 + 2 * n2, t3 = t2 + 3 * n3;
        int o, j;
        if (e < t1) { o = ei1[e]; j = 0; }
        else if (e < t2) { int x = e - t1; o = ei2[x]; j = 1 + (x >= n2 ? 1 : 0); }
        else if (e < t3) { int y = e - t2; o = ei3[y]; j = 3 + (y >= n3 ? 1 : 0) + (y >= 2 * n3 ? 1 : 0); }
        else return;
        atomicAdd(&counts[(size_t)j * n_obj + o], 1);
        atomicAdd(&counts[(size_t)6 * n_obj + o], 1);
    }
}

// ---- multi-block scan, phase 1: per-block (1024 elems) exclusive prefix + block sums ----
__launch_bounds__(256)
__global__ void scan1_k(const int* __restrict__ deg, int* __restrict__ rowptr,
                        int* __restrict__ bsum, int n)
{
    __shared__ int buf[256];
    int tid = threadIdx.x;
    int base = blockIdx.x * 1024 + tid * 4;
    int v[4];
#pragma unroll
    for (int k = 0; k < 4; ++k) { int i = base + k; v[k] = (i < n) ? deg[i] : 0; }
    int tsum = v[0] + v[1] + v[2] + v[3];
    buf[tid] = tsum;
    __syncthreads();
    for (int off = 1; off < 256; off <<= 1) {
        int t = (tid >= off) ? buf[tid - off] : 0;
        __syncthreads();
        buf[tid] += t;
        __syncthreads();
    }
    int run = buf[tid] - tsum;
#pragma unroll
    for (int k = 0; k < 4; ++k) {
        int i = base + k;
        if (i < n) rowptr[i] = run;
        run += v[k];
    }
    if (tid == 255) bsum[blockIdx.x] = buf[255];
}

// ---- scan phase 2: exclusive scan of block sums (nb <= 256), writes rowptr[n]=total ----
__launch_bounds__(256)
__global__ void scan2_k(int* __restrict__ bsum, int* __restrict__ rowptr, int n, int nb)
{
    __shared__ int buf[256];
    int tid = threadIdx.x;
    int v = (tid < nb) ? bsum[tid] : 0;
    buf[tid] = v;
    __syncthreads();
    for (int off = 1; off < 256; off <<= 1) {
        int t = (tid >= off) ? buf[tid - off] : 0;
        __syncthreads();
        buf[tid] += t;
        __syncthreads();
    }
    if (tid < nb) bsum[tid] = buf[tid] - v;
    if (tid == 255) rowptr[n] = buf[255];
}

// ---- scan phase 3: add block offsets, copy to cursor ----
__launch_bounds__(256)
__global__ void scan3_k(int* __restrict__ rowptr, int* __restrict__ cursor,
                        const int* __restrict__ bsum, int n)
{
    int i = blockIdx.x * 256 + threadIdx.x;
    if (i < n) {
        int r = rowptr[i] + bsum[i >> 10];
        rowptr[i] = r;
        cursor[i] = r;
    }
}

// ---- CSR inverse map: epos[e] = sorted position of entry e ----
__launch_bounds__(256)
__global__ void fill_k(const int* __restrict__ ei1, const int* __restrict__ ei2,
                       const int* __restrict__ ei3, int* __restrict__ cursor,
                       int* __restrict__ epos, int n1, int n2, int n3)
{
    int e = blockIdx.x * 256 + threadIdx.x;
    int t1 = n1, t2 = n1 + 2 * n2, t3 = t2 + 3 * n3;
    int o;
    if (e < t1) o = ei1[e];
    else if (e < t2) o = ei2[e - t1];
    else if (e < t3) o = ei3[e - t2];
    else return;
    epos[e] = atomicAdd(&cursor[o], 1);
}

// ---- fallback-path layer-0 agg ----
__launch_bounds__(256)
__global__ void bcast_k(const int* __restrict__ counts, const float* __restrict__ ac,
                        _Float16* __restrict__ aggh, int n_obj)
{
    __shared__ float ch[384];
    int tid = threadIdx.x;
    for (int i = tid; i < 384; i += 256) ch[i] = ac[i];
    __syncthreads();
    int i = blockIdx.x * 256 + tid;
    int o = i >> 3, q = i & 7;
    if (o < n_obj) {
        float c[6];
#pragma unroll
        for (int j = 0; j < 6; ++j) c[j] = (float)counts[(size_t)j * n_obj + o];
        h8 v;
#pragma unroll
        for (int comp = 0; comp < 8; ++comp) {
            int col = 8 * q + comp;
            float s = 0.f;
#pragma unroll
            for (int j = 0; j < 6; ++j) s = fmaf(c[j], ch[j * 64 + col], s);
            v[comp] = (_Float16)s;
        }
        *(h8*)(aggh + (size_t)o * 64 + 8 * q) = v;
    }
}

// ---- shared MLP_u tail: Ah staged [64 x 128 fp16, LDA=136] -> objh/aggf ----
__device__ __forceinline__ void update_tail(
    _Float16* __restrict__ Ah, _Float16* __restrict__ objh,
    const _Float16* __restrict__ W1h, const _Float16* __restrict__ W1l,
    const float* __restrict__ B1,
    const _Float16* __restrict__ W2h, const _Float16* __restrict__ W2l,
    const float* __restrict__ B2,
    int n_obj, int a_base, int last, float* __restrict__ aggf)
{
    constexpr int LDA = 136;
    const int tid = threadIdx.x;
    const int wave = tid >> 6, lane = tid & 63;
    const int r = lane & 15, g = lane >> 4;

    f32x4 z = {0.f, 0.f, 0.f, 0.f};
    f32x4 acc[4][2];
#pragma unroll
    for (int rt = 0; rt < 4; ++rt) { acc[rt][0] = z; acc[rt][1] = z; }
    {
        h8 bh[2][2], bl[2][2];
#pragma unroll
        for (int t = 0; t < 2; ++t) {
            size_t wo = (size_t)((wave * 2 + t) * 16 + r) * 128 + g * 8;
            bh[0][t] = *(const h8*)(W1h + wo);
            bl[0][t] = *(const h8*)(W1l + wo);
        }
#pragma unroll
        for (int kc = 0; kc < 4; ++kc) {
            const int cur = kc & 1, nxt = cur ^ 1;
            if (kc + 1 < 4) {
#pragma unroll
                for (int t = 0; t < 2; ++t) {
                    size_t wo = (size_t)((wave * 2 + t) * 16 + r) * 128 + (kc + 1) * 32 + g * 8;
                    bh[nxt][t] = *(const h8*)(W1h + wo);
                    bl[nxt][t] = *(const h8*)(W1l + wo);
                }
            }
            const int ko = kc * 32 + g * 8;
            h8 ah[4];
#pragma unroll
            for (int rt = 0; rt < 4; ++rt)
                ah[rt] = *(const h8*)(Ah + (rt * 16 + r) * LDA + ko);
#pragma unroll
            for (int t = 0; t < 2; ++t)
#pragma unroll
                for (int rt = 0; rt < 4; ++rt)
                    acc[rt][t] = mfma2(ah[rt], bh[cur][t], bl[cur][t], acc[rt][t]);
        }
    }
    __syncthreads();
#pragma unroll
    for (int t = 0; t < 2; ++t) {
        int col = (wave * 2 + t) * 16 + r;
        float b1 = B1[col];
#pragma unroll
        for (int rt = 0; rt < 4; ++rt)
#pragma unroll
            for (int q = 0; q < 4; ++q) {
                int row = rt * 16 + g * 4 + q;
                float h = acc[rt][t][q] + b1;
                h = h > 0.f ? h : 0.f;
                Ah[row * LDA + col] = (_Float16)h;
            }
    }
    __syncthreads();

    f32x4 acc2[4];
#pragma unroll
    for (int rt = 0; rt < 4; ++rt) acc2[rt] = z;
    {
        h8 bh[2], bl[2];
        {
            size_t wo = (size_t)(wave * 16 + r) * 128 + g * 8;
            bh[0] = *(const h8*)(W2h + wo);
            bl[0] = *(const h8*)(W2l + wo);
        }
#pragma unroll
        for (int kc = 0; kc < 4; ++kc) {
            const int cur = kc & 1, nxt = cur ^ 1;
            if (kc + 1 < 4) {
                size_t wo = (size_t)(wave * 16 + r) * 128 + (kc + 1) * 32 + g * 8;
                bh[nxt] = *(const h8*)(W2h + wo);
                bl[nxt] = *(const h8*)(W2l + wo);
            }
            const int ko = kc * 32 + g * 8;
#pragma unroll
            for (int rt = 0; rt < 4; ++rt) {
                h8 ah = *(const h8*)(Ah + (rt * 16 + r) * LDA + ko);
                acc2[rt] = mfma2(ah, bh[cur], bl[cur], acc2[rt]);
            }
        }
    }
    {
        int col = wave * 16 + r;
        float b2 = B2[col];
#pragma unroll
        for (int rt = 0; rt < 4; ++rt)
#pragma unroll
            for (int q = 0; q < 4; ++q) {
                int row = a_base + rt * 16 + g * 4 + q;
                if (row < n_obj) {
                    float v = acc2[rt][q] + b2;
                    if (last) aggf[(size_t)row * 64 + col] = v;
                    else objh[(size_t)row * 64 + col] = (_Float16)v;
                }
            }
    }
}

// ---- layer-0 update with inline bcast (obj=0, agg from counts x ac) ----
__launch_bounds__(256, 4)
__global__ void update0_bcast(_Float16* __restrict__ objh,
                              const int* __restrict__ counts, const float* __restrict__ ac,
                              const _Float16* __restrict__ W1h, const _Float16* __restrict__ W1l,
                              const float* __restrict__ B1,
                              const _Float16* __restrict__ W2h, const _Float16* __restrict__ W2l,
                              const float* __restrict__ B2, int n_obj)
{
    constexpr int LDA = 136;
    __shared__ _Float16 Ah[64 * LDA];
    __shared__ float ch[384];
    const int tid = threadIdx.x;
    const int a_base = blockIdx.x * 64;

    for (int i = tid; i < 384; i += 256) ch[i] = ac[i];
    __syncthreads();
#pragma unroll
    for (int i = 0; i < 4; ++i) {
        int f = tid + 256 * i;
        int a = f >> 4, c = f & 15;
        int rg = a_base + a; if (rg >= n_obj) rg = n_obj - 1;
        h8 v;
        if (c < 8) {
            v = (h8)(_Float16)0.f;
        } else {
            float cc[6];
#pragma unroll
            for (int j = 0; j < 6; ++j) cc[j] = (float)counts[(size_t)j * n_obj + rg];
#pragma unroll
            for (int comp = 0; comp < 8; ++comp) {
                int col = (c - 8) * 8 + comp;
                float s = 0.f;
#pragma unroll
                for (int j = 0; j < 6; ++j) s = fmaf(cc[j], ch[j * 64 + col], s);
                v[comp] = (_Float16)s;
            }
        }
        *(h8*)(Ah + a * LDA + c * 8) = v;
    }
    __syncthreads();
    update_tail(Ah, objh, W1h, W1l, B1, W2h, W2l, B2, n_obj, a_base, 0, nullptr);
}

// ---- fallback update (reads fp16 aggh) ----
template<int FIRST>
__launch_bounds__(256, 4)
__global__ void update_mfma(_Float16* __restrict__ objh, _Float16* __restrict__ aggh,
                            const _Float16* __restrict__ W1h, const _Float16* __restrict__ W1l,
                            const float* __restrict__ B1,
                            const _Float16* __restrict__ W2h, const _Float16* __restrict__ W2l,
                            const float* __restrict__ B2,
                            int n_obj, int zero_agg, int last, float* __restrict__ aggf)
{
    constexpr int LDA = 136;
    __shared__ _Float16 Ah[64 * LDA];
    const int tid = threadIdx.x;
    const int a_base = blockIdx.x * 64;
#pragma unroll
    for (int i = 0; i < 4; ++i) {
        int f = tid + 256 * i;
        int a = f >> 4, c = f & 15;
        int rg = a_base + a; if (rg >= n_obj) rg = n_obj - 1;
        h8 v;
        if (c < 8) {
            if (FIRST) v = (h8)(_Float16)0.f;
            else v = *(const h8*)(objh + (size_t)rg * 64 + c * 8);
        } else {
            v = *(const h8*)(aggh + (size_t)rg * 64 + (c - 8) * 8);
        }
        *(h8*)(Ah + a * LDA + c * 8) = v;
    }
    __syncthreads();
    update_tail(Ah, objh, W1h, W1l, B1, W2h, W2l, B2, n_obj, a_base, last, aggf);
    if (zero_agg) {
        __syncthreads();
        h8 zz = (h8)(_Float16)0.f;
#pragma unroll
        for (int i = 0; i < 2; ++i) {
            int f = tid + 256 * i;
            int a = f >> 3, q = f & 7;
            int rg = a_base + a;
            if (rg < n_obj) *(h8*)(aggh + (size_t)rg * 64 + q * 8) = zz;
        }
    }
}

// ---- fused pred body; STORE=1: full-line chunk stores at CSR pos; STORE=0: atomics ----
template<int R, int STORE>
__device__ __forceinline__ void pred_body(
    char* smem,
    const _Float16* __restrict__ objh, const int* __restrict__ ei,
    const int* __restrict__ epos, int cbase,
    const _Float16* __restrict__ W1h, const _Float16* __restrict__ W1l,
    const float* __restrict__ B1,
    const _Float16* __restrict__ W2h, const _Float16* __restrict__ W2l,
    const float* __restrict__ B2,
    _Float16* __restrict__ aggh, _Float16* __restrict__ chunks,
    int n_atoms, int blk)
{
    constexpr int D = 64 * R;
    constexpr int KC = D / 32;
    constexpr int LDA = D + 8;
    _Float16* Ah = (_Float16*)smem;
    int* eis = (int*)(Ah + 64 * LDA);

    const int tid = threadIdx.x;
    const int wave = tid >> 6, lane = tid & 63;
    const int r = lane & 15, g = lane >> 4;
    const int a_base = blk * 64;
    const int tb = wave * R;

    for (int i = tid; i < R * 64; i += 256) {
        int s = i >> 6, a = i & 63;
        int ag = a_base + a; if (ag >= n_atoms) ag = n_atoms - 1;
        eis[i] = ei[s * n_atoms + ag];
    }
    __syncthreads();
    {
        h8 vv[2 * R];
#pragma unroll
        for (int i = 0; i < 2 * R; ++i) {
            int f = tid + 256 * i;
            int rowslot = f >> 3, c = f & 7;
            int s = rowslot >> 6, a = rowslot & 63;
            vv[i] = *(const h8*)(objh + (size_t)eis[s * 64 + a] * 64 + c * 8);
        }
#pragma unroll
        for (int i = 0; i < 2 * R; ++i) {
            int f = tid + 256 * i;
            int rowslot = f >> 3, c = f & 7;
            int s = rowslot >> 6, a = rowslot & 63;
            *(h8*)(Ah + a * LDA + s * 64 + c * 8) = vv[i];
        }
    }
    __syncthreads();

    f32x4 z = {0.f, 0.f, 0.f, 0.f};
    f32x4 acc[4][R];
#pragma unroll
    for (int rt = 0; rt < 4; ++rt)
#pragma unroll
        for (int t = 0; t < R; ++t) acc[rt][t] = z;

    // ---- GEMM1 ----
    {
        h8 bh[2][R], bl[2][R];
#pragma unroll
        for (int t = 0; t < R; ++t) {
            size_t wo = (size_t)((tb + t) * 16 + r) * D + g * 8;
            bh[0][t] = *(const h8*)(W1h + wo);
            bl[0][t] = *(const h8*)(W1l + wo);
        }
#pragma unroll
        for (int kc = 0; kc < KC; ++kc) {
            const int cur = kc & 1, nxt = cur ^ 1;
            if (kc + 1 < KC) {
#pragma unroll
                for (int t = 0; t < R; ++t) {
                    size_t wo = (size_t)((tb + t) * 16 + r) * D + (kc + 1) * 32 + g * 8;
                    bh[nxt][t] = *(const h8*)(W1h + wo);
                    bl[nxt][t] = *(const h8*)(W1l + wo);
                }
            }
            const int ko = kc * 32 + g * 8;
            h8 ah[4];
#pragma unroll
            for (int rt = 0; rt < 4; ++rt)
                ah[rt] = *(const h8*)(Ah + (rt * 16 + r) * LDA + ko);
#pragma unroll
            for (int t = 0; t < R; ++t)
#pragma unroll
                for (int rt = 0; rt < 4; ++rt)
                    acc[rt][t] = mfma2(ah[rt], bh[cur][t], bl[cur][t], acc[rt][t]);
        }
    }
    __syncthreads();
#pragma unroll
    for (int t = 0; t < R; ++t) {
        int col = (tb + t) * 16 + r;
        float b1 = B1[col];
#pragma unroll
        for (int rt = 0; rt < 4; ++rt)
#pragma unroll
            for (int q = 0; q < 4; ++q) {
                int row = rt * 16 + g * 4 + q;
                float h = acc[rt][t][q] + b1;
                h = h > 0.f ? h : 0.f;
                Ah[row * LDA + col] = (_Float16)h;
            }
    }
    __syncthreads();

    // ---- GEMM2 ----
#pragma unroll
    for (int rt = 0; rt < 4; ++rt)
#pragma unroll
        for (int t = 0; t < R; ++t) acc[rt][t] = z;
    {
        h8 bh[2][R], bl[2][R];
#pragma unroll
        for (int t = 0; t < R; ++t) {
            size_t wo = (size_t)((tb + t) * 16 + r) * D + g * 8;
            bh[0][t] = *(const h8*)(W2h + wo);
            bl[0][t] = *(const h8*)(W2l + wo);
        }
#pragma unroll
        for (int kc = 0; kc < KC; ++kc) {
            const int cur = kc & 1, nxt = cur ^ 1;
            if (kc + 1 < KC) {
#pragma unroll
                for (int t = 0; t < R; ++t) {
                    size_t wo = (size_t)((tb + t) * 16 + r) * D + (kc + 1) * 32 + g * 8;
                    bh[nxt][t] = *(const h8*)(W2h + wo);
                    bl[nxt][t] = *(const h8*)(W2l + wo);
                }
            }
            const int ko = kc * 32 + g * 8;
            h8 ah[4];
#pragma unroll
            for (int rt = 0; rt < 4; ++rt)
                ah[rt] = *(const h8*)(Ah + (rt * 16 + r) * LDA + ko);
#pragma unroll
            for (int t = 0; t < R; ++t)
#pragma unroll
                for (int rt = 0; rt < 4; ++rt)
                    acc[rt][t] = mfma2(ah[rt], bh[cur][t], bl[cur][t], acc[rt][t]);
        }
    }

    if (STORE) {
        __syncthreads();
#pragma unroll
        for (int t = 0; t < R; ++t) {
            int col = (tb + t) * 16 + r;
            float b2 = B2[col];
            int s = col >> 6, cc = col & 63;
#pragma unroll
            for (int rt = 0; rt < 4; ++rt)
#pragma unroll
                for (int q = 0; q < 4; ++q) {
                    int row = rt * 16 + g * 4 + q;
                    Ah[row * LDA + s * 64 + cc] = (_Float16)(acc[rt][t][q] + b2);
                }
        }
        __syncthreads();
#pragma unroll
        for (int p = 0; p < 2 * R; ++p) {
            int i = p * 32 + (tid >> 3);
            int s = i >> 6, a = i & 63;
            int c8 = tid & 7;
            int atom = a_base + a;
            if (atom < n_atoms) {
                int pos = epos[cbase + s * n_atoms + atom];
                *(h8*)(chunks + (size_t)pos * 64 + c8 * 8) =
                    *(const h8*)(Ah + a * LDA + s * 64 + c8 * 8);
            }
        }
    } else {
#pragma unroll
        for (int t = 0; t < R; ++t) {
            int col = (tb + t) * 16 + r;
            float b2 = B2[col];
            int s = col >> 6, cc = col & 63;
#pragma unroll
            for (int rt = 0; rt < 4; ++rt)
#pragma unroll
                for (int q = 0; q < 4; ++q) {
                    int row = rt * 16 + g * 4 + q;
                    int atom = a_base + row;
                    float v = acc[rt][t][q] + b2;
                    float v2 = __shfl_xor(v, 1);
                    if (atom < n_atoms && (r & 1) == 0) {
                        __half2 hv = __floats2half2_rn(v, v2);
                        unsafeAtomicAdd((__half2*)(aggh + (size_t)eis[s * 64 + row] * 64 + cc), hv);
                    }
                }
        }
    }
}

template<int STORE>
__launch_bounds__(256, 6)
__global__ void pred_all(const _Float16* __restrict__ objh, _Float16* __restrict__ aggh,
                         _Float16* __restrict__ chunks, const int* __restrict__ epos,
                         const int* __restrict__ ei1, const int* __restrict__ ei2,
                         const int* __restrict__ ei3,
                         const _Float16* __restrict__ hb,
                         const float* __restrict__ b_p1_1, const float* __restrict__ b_p1_2,
                         const float* __restrict__ b_p2_1, const float* __restrict__ b_p2_2,
                         const float* __restrict__ b_p3_1, const float* __restrict__ b_p3_2,
                         int n1, int n2, int n3, int nb3, int nb2)
{
    extern __shared__ char smem[];
    int b = blockIdx.x;
    if (b < nb3) {
        pred_body<3, STORE>(smem, objh, ei3, epos, n1 + 2 * n2,
                            hb + 81920, hb + 118784, b_p3_1,
                            hb + 155648, hb + 192512, b_p3_2, aggh, chunks, n3, b);
    } else if (b < nb3 + nb2) {
        pred_body<2, STORE>(smem, objh, ei2, epos, n1,
                            hb + 16384, hb + 32768, b_p2_1,
                            hb + 49152, hb + 65536, b_p2_2, aggh, chunks, n2, b - nb3);
    } else {
        pred_body<1, STORE>(smem, objh, ei1, epos, 0,
                            hb + 0, hb + 4096, b_p1_1,
                            hb + 8192, hb + 12288, b_p1_2, aggh, chunks, n1, b - nb3 - nb2);
    }
}

// ---- fused fanin (contiguous CSR stream, 2x unrolled) + update MLP ----
__launch_bounds__(256, 4)
__global__ void fanin_update(_Float16* __restrict__ objh,
                             const _Float16* __restrict__ chunks,
                             const int* __restrict__ rowptr,
                             const _Float16* __restrict__ W1h, const _Float16* __restrict__ W1l,
                             const float* __restrict__ B1,
                             const _Float16* __restrict__ W2h, const _Float16* __restrict__ W2l,
                             const float* __restrict__ B2,
                             int n_obj, int last, float* __restrict__ aggf)
{
    constexpr int LDA = 136;
    __shared__ _Float16 Ah[64 * LDA];

    const int tid = threadIdx.x;
    const int a_base = blockIdx.x * 64;

    const int o_local = tid >> 2, part = tid & 3;
    const int o = a_base + o_local;
    const bool valid = o < n_obj;
    const int b = valid ? rowptr[o] : 0;
    const int e2 = valid ? rowptr[o + 1] : 0;
    float s[16];
#pragma unroll
    for (int j = 0; j < 16; ++j) s[j] = 0.f;
    int i = b;
    for (; i + 2 <= e2; i += 2) {
        const h8* c0 = (const h8*)(chunks + (size_t)i * 64 + part * 16);
        const h8* c1 = (const h8*)(chunks + (size_t)(i + 1) * 64 + part * 16);
        h8 a0 = c0[0], a1 = c0[1], d0 = c1[0], d1 = c1[1];
#pragma unroll
        for (int j = 0; j < 8; ++j) {
            s[j] += (float)a0[j] + (float)d0[j];
            s[8 + j] += (float)a1[j] + (float)d1[j];
        }
    }
    if (i < e2) {
        const h8* c0 = (const h8*)(chunks + (size_t)i * 64 + part * 16);
        h8 a0 = c0[0], a1 = c0[1];
#pragma unroll
        for (int j = 0; j < 8; ++j) { s[j] += (float)a0[j]; s[8 + j] += (float)a1[j]; }
    }
    {
        int oc = valid ? o : n_obj - 1;
        h8 u0 = *(const h8*)(objh + (size_t)oc * 64 + part * 16);
        h8 u1 = *(const h8*)(objh + (size_t)oc * 64 + part * 16 + 8);
        *(h8*)(Ah + o_local * LDA + part * 16) = u0;
        *(h8*)(Ah + o_local * LDA + part * 16 + 8) = u1;
        h8 a0, a1;
#pragma unroll
        for (int j = 0; j < 8; ++j) { a0[j] = (_Float16)s[j]; a1[j] = (_Float16)s[8 + j]; }
        *(h8*)(Ah + o_local * LDA + 64 + part * 16) = a0;
        *(h8*)(Ah + o_local * LDA + 64 + part * 16 + 8) = a1;
    }
    __syncthreads();
    update_tail(Ah, objh, W1h, W1l, B1, W2h, W2l, B2, n_obj, a_base, last, aggf);
}

__global__ void pool_kernel(const float* __restrict__ obj, const int* __restrict__ batch,
                            float* __restrict__ pooled, int n_obj)
{
    int i = blockIdx.x * 256 + threadIdx.x;
    int row = i >> 4, q = i & 15;
    if (row < n_obj) {
        float4 v = ((const float4*)obj)[(size_t)row * 16 + q];
        int g = batch[row];
        float* p = pooled + g * 64 + 4 * q;
        atomicAdd(p + 0, v.x);
        atomicAdd(p + 1, v.y);
        atomicAdd(p + 2, v.z);
        atomicAdd(p + 3, v.w);
    }
}

__launch_bounds__(128)
__global__ void readout_kernel(const float* __restrict__ pooled,
                               const float* __restrict__ w1, const float* __restrict__ b1,
                               const float* __restrict__ w2, const float* __restrict__ b2,
                               float* __restrict__ out)
{
    int g = blockIdx.x, c = threadIdx.x;
    __shared__ float xs[64];
    __shared__ float red[2];
    if (c < 64) xs[c] = pooled[g * 64 + c];
    __syncthreads();
    float h = b1[c];
#pragma unroll
    for (int k = 0; k < 64; ++k) h = fmaf(xs[k], w1[k * 128 + c], h);
    float v = fmaxf(h, 0.f) * w2[c];
#pragma unroll
    for (int off = 32; off > 0; off >>= 1) v += __shfl_down(v, off);
    if ((c & 63) == 0) red[c >> 6] = v;
    __syncthreads();
    if (c == 0) out[g] = red[0] + red[1] + b2[0];
}

static inline size_t align_up(size_t x) { return (x + 255) & ~(size_t)255; }

extern "C" void kernel_launch(void* const* d_in, const int* in_sizes, int n_in,
                              void* d_out, int out_size, void* d_ws, size_t ws_size,
                              hipStream_t stream)
{
    const float* w_p1_1 = (const float*)d_in[4];
    const float* b_p1_1 = (const float*)d_in[5];
    const float* w_p1_2 = (const float*)d_in[6];
    const float* b_p1_2 = (const float*)d_in[7];
    const float* w_p2_1 = (const float*)d_in[8];
    const float* b_p2_1 = (const float*)d_in[9];
    const float* w_p2_2 = (const float*)d_in[10];
    const float* b_p2_2 = (const float*)d_in[11];
    const float* w_p3_1 = (const float*)d_in[12];
    const float* b_p3_1 = (const float*)d_in[13];
    const float* w_p3_2 = (const float*)d_in[14];
    const float* b_p3_2 = (const float*)d_in[15];
    const float* w_u1 = (const float*)d_in[16];
    const float* b_u1 = (const float*)d_in[17];
    const float* w_u2 = (const float*)d_in[18];
    const float* b_u2 = (const float*)d_in[19];
    const float* w_r1 = (const float*)d_in[20];
    const float* b_r1 = (const float*)d_in[21];
    const float* w_r2 = (const float*)d_in[22];
    const float* b_r2 = (const float*)d_in[23];
    const int* ei_p1 = (const int*)d_in[24];
    const int* ei_p2 = (const int*)d_in[25];
    const int* ei_p3 = (const int*)d_in[26];
    const int* batch = (const int*)d_in[27];

    const int n_obj = in_sizes[0];
    const int n_p1 = in_sizes[24];
    const int n_p2 = in_sizes[25] / 2;
    const int n_p3 = in_sizes[26] / 3;
    const int E = n_p1 + 2 * n_p2 + 3 * n_p3;

    char* base = (char*)d_ws;
    size_t off = 0;
    _Float16* objh = (_Float16*)(base + off); off = align_up(off + (size_t)n_obj * 64 * 2);
    _Float16* aggh = (_Float16*)(base + off); off = align_up(off + (size_t)n_obj * 64 * 2);
    float* aggf = (float*)(base + off);       off = align_up(off + (size_t)n_obj * 64 * 4);
    float* pooled = (float*)(base + off);     off = align_up(off + (size_t)out_size * 64 * 4);
    _Float16* hb = (_Float16*)(base + off);   off = align_up(off + (size_t)278528 * 2);
    int* counts = (int*)(base + off);         off = align_up(off + (size_t)7 * n_obj * 4);
    int* deg = counts + (size_t)6 * n_obj;
    int* rowptr = (int*)(base + off);         off = align_up(off + ((size_t)n_obj + 1) * 4);
    int* cursor = (int*)(base + off);         off = align_up(off + (size_t)n_obj * 4);
    int* bsum = (int*)(base + off);           off = align_up(off + 256 * 4);
    int* epos = (int*)(base + off);           off = align_up(off + (size_t)E * 4);
    _Float16* chunks = (_Float16*)(base + off); off = align_up(off + (size_t)E * 64 * 2);
    const bool csr_ok = off <= ws_size;
    float* ac = pooled;   // 384 floats; pooled re-zeroed after layers

    const int nb3 = (n_p3 + 63) / 64, nb2 = (n_p2 + 63) / 64, nb1 = (n_p1 + 63) / 64;
    const int pred_smem = 64 * (192 + 8) * 2 + 3 * 64 * 4;  // 26368 B
    const int nbs = (n_obj + 1023) / 1024;                  // scan blocks (<=256)

    hipMemsetAsync(counts, 0, (size_t)7 * n_obj * sizeof(int), stream);
    setup_k<<<547 + (E + 255) / 256, 256, 0, stream>>>(
        w_p1_1, w_p1_2, w_p2_1, w_p2_2, w_p3_1, w_p3_2, w_u1, w_u2, hb,
        b_p1_1, b_p1_2, b_p2_1, b_p2_2, b_p3_1, b_p3_2, ac,
        ei_p1, ei_p2, ei_p3, counts, n_obj, n_p1, n_p2, n_p3);
    if (csr_ok) {
        scan1_k<<<nbs, 256, 0, stream>>>(deg, rowptr, bsum, n_obj);
        scan2_k<<<1, 256, 0, stream>>>(bsum, rowptr, n_obj, nbs);
        scan3_k<<<(n_obj + 255) / 256, 256, 0, stream>>>(rowptr, cursor, bsum, n_obj);
        fill_k<<<(E + 255) / 256, 256, 0, stream>>>(ei_p1, ei_p2, ei_p3, cursor, epos,
                                                    n_p1, n_p2, n_p3);
        update0_bcast<<<(n_obj + 63) / 64, 256, 0, stream>>>(
            objh, counts, ac, hb + 229376, hb + 245760, b_u1,
            hb + 262144, hb + 270336, b_u2, n_obj);
        for (int l = 1; l < 3; ++l) {
            pred_all<1><<<nb3 + nb2 + nb1, 256, pred_smem, stream>>>(
                objh, aggh, chunks, epos, ei_p1, ei_p2, ei_p3, hb,
                b_p1_1, b_p1_2, b_p2_1, b_p2_2, b_p3_1, b_p3_2,
                n_p1, n_p2, n_p3, nb3, nb2);
            fanin_update<<<(n_obj + 63) / 64, 256, 0, stream>>>(
                objh, chunks, rowptr,
                hb + 229376, hb + 245760, b_u1, hb + 262144, hb + 270336, b_u2,
                n_obj, l == 2 ? 1 : 0, aggf);
        }
    } else {
        bcast_k<<<((size_t)n_obj * 8 + 255) / 256, 256, 0, stream>>>(counts, ac, aggh, n_obj);
        update_mfma<1><<<(n_obj + 63) / 64, 256, 0, stream>>>(
            objh, aggh, hb + 229376, hb + 245760, b_u1, hb + 262144, hb + 270336, b_u2,
            n_obj, 1, 0, aggf);
        for (int l = 1; l < 3; ++l) {
            pred_all<0><<<nb3 + nb2 + nb1, 256, pred_smem, stream>>>(
                objh, aggh, chunks, epos, ei_p1, ei_p2, ei_p3, hb,
                b_p1_1, b_p1_2, b_p2_1, b_p2_2, b_p3_1, b_p3_2,
                n_p1, n_p2, n_p3, nb3, nb2);
            update_mfma<0><<<(n_obj + 63) / 64, 256, 0, stream>>>(
                objh, aggh, hb + 229376, hb + 245760, b_u1, hb + 262144, hb + 270336, b_u2,
                n_obj, l < 2 ? 1 : 0, l == 2 ? 1 : 0, aggf);
        }
    }
    hipMemsetAsync(pooled, 0, (size_t)out_size * 64 * sizeof(float), stream);
    pool_kernel<<<((size_t)n_obj * 16 + 255) / 256, 256, 0, stream>>>(aggf, batch, pooled, n_obj);
    readout_kernel<<<out_size, 128, 0, stream>>>(pooled, w_r1, b_r1, w_r2, b_r2, (float*)d_out);
}